// Round 10
// baseline (60.834 us; speedup 1.0000x reference)
//
#include <hip/hip_runtime.h>
#include <hip/hip_bf16.h>

#define P 128
#define NH 16
#define POS_BND 102
#define RPE_NUM 205            // 2*POS_BND+1
#define TROWS 615              // 3*RPE_NUM
#define HALF_OFF 2460          // uint offset of half-table B (heads 8..15)
#define ROWS_PER_BLOCK 16

typedef float floatx4 __attribute__((ext_vector_type(4)));

__device__ __forceinline__ float blo(unsigned d) { return __uint_as_float(d << 16); }
__device__ __forceinline__ float bhi(unsigned d) { return __uint_as_float(d & 0xffff0000u); }
__device__ __forceinline__ unsigned pkbf(float a, float b) {
    unsigned r;
    asm("v_cvt_pk_bf16_f32 %0, %1, %2" : "=v"(r) : "v"(a), "v"(b));
    return r;   // low16 = bf16(a), high16 = bf16(b)
}

__global__ __launch_bounds__(256, 3)
void rpe_kernel(const int* __restrict__ xyz, const float* __restrict__ table,
                float* __restrict__ out) {
    // two compact half-tables, 16B rows (8 bank-windows for random b128 gathers)
    __shared__ unsigned lt[2 * HALF_OFF];     // 19680 B
    // per-wave: 8 heads x (4 rows x 64 j-pairs) bf16-packed
    __shared__ unsigned su[4][8][256];        // 32768 B; total 52448 B -> 3 blocks/CU

    const int t = threadIdx.x;
    const int w = t >> 6, l = t & 63;

    // ---- stage table as bf16 pairs: half A = heads 0..7, half B = heads 8..15 ----
    for (int q = t; q < TROWS * 8; q += 256) {
        int row = q >> 3, d = q & 7;
        float2 v = reinterpret_cast<const float2*>(table)[row * 8 + d];
        unsigned a = (__float_as_uint(v.x) + 0x8000u) >> 16;
        unsigned b = (__float_as_uint(v.y) + 0x8000u) & 0xffff0000u;
        int dst = (d < 4) ? (row * 4 + d) : (HALF_OFF + row * 4 + (d - 4));
        lt[dst] = a | b;
    }

    // wave pair shares 8 rows; w&1 selects head half (0..7 or 8..15)
    const int pair = w >> 1;
    const int hsel = w & 1;
    const int hoff = hsel ? HALF_OFF : 0;
    const int r0 = blockIdx.x * ROWS_PER_BLOCK + pair * 8;
    const int2* xp = reinterpret_cast<const int2*>(xyz);

    // prefetch task 0 (rows r0..r0+3); lane l covers j = 2l, 2l+1 -> 3 int2 per row
    int2 pA0, pA1, pA2, pB0, pB1, pB2, pC0, pC1, pC2, pD0, pD1, pD2;
    {
        size_t ba = (size_t)192 * r0 + 3 * l;
        pA0 = xp[ba];       pA1 = xp[ba + 1];       pA2 = xp[ba + 2];
        pB0 = xp[ba + 192]; pB1 = xp[ba + 193];     pB2 = xp[ba + 194];
        pC0 = xp[ba + 384]; pC1 = xp[ba + 385];     pC2 = xp[ba + 386];
        pD0 = xp[ba + 576]; pD1 = xp[ba + 577];     pD2 = xp[ba + 578];
    }
    __syncthreads();   // the ONLY barrier (table visibility)

    // one row's work: clamp 6 coords, 6 b128 gathers, 8 transposed bf16-pair writes
#define ROWJOB(ca, cb, cc, s)                                                        \
    {                                                                                \
        const int t00 = min(max((ca).x, -POS_BND), POS_BND) + POS_BND;               \
        const int t01 = min(max((ca).y, -POS_BND), POS_BND) + POS_BND + RPE_NUM;     \
        const int t02 = min(max((cb).x, -POS_BND), POS_BND) + POS_BND + 2 * RPE_NUM; \
        const int t10 = min(max((cb).y, -POS_BND), POS_BND) + POS_BND;               \
        const int t11 = min(max((cc).x, -POS_BND), POS_BND) + POS_BND + RPE_NUM;     \
        const int t12 = min(max((cc).y, -POS_BND), POS_BND) + POS_BND + 2 * RPE_NUM; \
        uint4 ga0 = *reinterpret_cast<const uint4*>(&lt[hoff + t00 * 4]);            \
        uint4 ga1 = *reinterpret_cast<const uint4*>(&lt[hoff + t01 * 4]);            \
        uint4 ga2 = *reinterpret_cast<const uint4*>(&lt[hoff + t02 * 4]);            \
        uint4 gc0 = *reinterpret_cast<const uint4*>(&lt[hoff + t10 * 4]);            \
        uint4 gc1 = *reinterpret_cast<const uint4*>(&lt[hoff + t11 * 4]);            \
        uint4 gc2 = *reinterpret_cast<const uint4*>(&lt[hoff + t12 * 4]);            \
        unsigned* srow = &su[w][0][(s) * 64 + l];                                    \
        srow[0*256] = pkbf(blo(ga0.x)+blo(ga1.x)+blo(ga2.x), blo(gc0.x)+blo(gc1.x)+blo(gc2.x)); \
        srow[1*256] = pkbf(bhi(ga0.x)+bhi(ga1.x)+bhi(ga2.x), bhi(gc0.x)+bhi(gc1.x)+bhi(gc2.x)); \
        srow[2*256] = pkbf(blo(ga0.y)+blo(ga1.y)+blo(ga2.y), blo(gc0.y)+blo(gc1.y)+blo(gc2.y)); \
        srow[3*256] = pkbf(bhi(ga0.y)+bhi(ga1.y)+bhi(ga2.y), bhi(gc0.y)+bhi(gc1.y)+bhi(gc2.y)); \
        srow[4*256] = pkbf(blo(ga0.z)+blo(ga1.z)+blo(ga2.z), blo(gc0.z)+blo(gc1.z)+blo(gc2.z)); \
        srow[5*256] = pkbf(bhi(ga0.z)+bhi(ga1.z)+bhi(ga2.z), bhi(gc0.z)+bhi(gc1.z)+bhi(gc2.z)); \
        srow[6*256] = pkbf(blo(ga0.w)+blo(ga1.w)+blo(ga2.w), blo(gc0.w)+blo(gc1.w)+blo(gc2.w)); \
        srow[7*256] = pkbf(bhi(ga0.w)+bhi(ga1.w)+bhi(ga2.w), bhi(gc0.w)+bhi(gc1.w)+bhi(gc2.w)); \
    }

    #pragma unroll
    for (int k = 0; k < 2; ++k) {            // 2 tasks x 4 rows = 8 rows per wave
        const int ra = r0 + 4 * k;           // rows ra..ra+3 -> 2KB contiguous runs
        const int b  = ra >> 7;
        const int i  = ra & 127;

        int2 cA0 = pA0, cA1 = pA1, cA2 = pA2, cB0 = pB0, cB1 = pB1, cB2 = pB2;
        int2 cC0 = pC0, cC1 = pC1, cC2 = pC2, cD0 = pD0, cD1 = pD1, cD2 = pD2;
        if (k == 0) {                        // prefetch next task's 4 rows
            size_t ba = (size_t)192 * (ra + 4) + 3 * l;
            pA0 = xp[ba];       pA1 = xp[ba + 1];   pA2 = xp[ba + 2];
            pB0 = xp[ba + 192]; pB1 = xp[ba + 193]; pB2 = xp[ba + 194];
            pC0 = xp[ba + 384]; pC1 = xp[ba + 385]; pC2 = xp[ba + 386];
            pD0 = xp[ba + 576]; pD1 = xp[ba + 577]; pD2 = xp[ba + 578];
        }

        ROWJOB(cA0, cA1, cA2, 0)
        ROWJOB(cB0, cB1, cB2, 1)
        ROWJOB(cC0, cC1, cC2, 2)
        ROWJOB(cD0, cD1, cD2, 3)

        // ---- store: per head, 2 consecutive NT dwordx4 = one 2KB contiguous run ----
        // readback uint2 at 2l: banks tile evenly (2 lanes/bank, free)
        const size_t rbase = ((size_t)(b * NH + hsel * 8)) * (P * P) + (size_t)i * P + 4 * l;
        #pragma unroll
        for (int h = 0; h < 8; ++h) {
            #pragma unroll
            for (int pt = 0; pt < 2; ++pt) {
                uint2 v = *reinterpret_cast<const uint2*>(&su[w][h][pt * 128 + 2 * l]);
                floatx4 f = { blo(v.x), bhi(v.x), blo(v.y), bhi(v.y) };
                __builtin_nontemporal_store(f,
                    reinterpret_cast<floatx4*>(out + rbase + (size_t)h * (P * P) + pt * 256));
            }
        }
    }
#undef ROWJOB
}

extern "C" void kernel_launch(void* const* d_in, const int* in_sizes, int n_in,
                              void* d_out, int out_size, void* d_ws, size_t ws_size,
                              hipStream_t stream) {
    const int*   xyz   = (const int*)d_in[0];
    const float* table = (const float*)d_in[1];
    float*       out   = (float*)d_out;

    const int total_rows = 256 * P;                   // 32768
    const int grid = total_rows / ROWS_PER_BLOCK;     // 2048
    rpe_kernel<<<grid, 256, 0, stream>>>(xyz, table, out);
}

// Round 11
// 54.868 us; speedup vs baseline: 1.1087x; 1.1087x over previous
//
#include <hip/hip_runtime.h>
#include <hip/hip_bf16.h>

#define P 128
#define NH 16
#define POS_BND 102
#define RPE_NUM 205            // 2*POS_BND+1
#define TROWS 615              // 3*RPE_NUM
#define HALF_OFF 2460          // uint offset of half-table B (heads 8..15)
#define ROWS_PER_BLOCK 16

// Best-known configuration (R5, 54.9 us):
//  - bf16 table in LDS, split into two 16B-row half-tables (8 bank windows)
//  - per-wave 2rows x 16heads bf16-packed transpose buffer (no main-loop barriers)
//  - 1KB contiguous NT store runs per head (NT is +32%: R8 A/B)
//  - 3 blocks/CU (52.4KB LDS); 12 waves/CU proven sufficient (R7/R9 null)

typedef float floatx4 __attribute__((ext_vector_type(4)));

__device__ __forceinline__ float blo(unsigned d) { return __uint_as_float(d << 16); }
__device__ __forceinline__ float bhi(unsigned d) { return __uint_as_float(d & 0xffff0000u); }
__device__ __forceinline__ unsigned pkbf(float a, float b) {
    unsigned r;
    asm("v_cvt_pk_bf16_f32 %0, %1, %2" : "=v"(r) : "v"(a), "v"(b));
    return r;   // low16 = bf16(a), high16 = bf16(b)
}

__global__ __launch_bounds__(256, 3)
void rpe_kernel(const int* __restrict__ xyz, const float* __restrict__ table,
                float* __restrict__ out) {
    __shared__ unsigned lt[2 * HALF_OFF];     // 19680 B
    __shared__ unsigned su[4][NH][128];       // 32768 B; total 52448 B -> 3 blocks/CU

    const int t = threadIdx.x;
    const int w = t >> 6, l = t & 63;

    // ---- stage table as bf16 pairs: half A = heads 0..7, half B = heads 8..15 ----
    for (int q = t; q < TROWS * 8; q += 256) {
        int row = q >> 3, d = q & 7;
        float2 v = reinterpret_cast<const float2*>(table)[row * 8 + d];
        unsigned a = (__float_as_uint(v.x) + 0x8000u) >> 16;
        unsigned b = (__float_as_uint(v.y) + 0x8000u) & 0xffff0000u;
        int dst = (d < 4) ? (row * 4 + d) : (HALF_OFF + row * 4 + (d - 4));
        lt[dst] = a | b;
    }

    const int r0 = blockIdx.x * ROWS_PER_BLOCK + 4 * w;   // wave's first row
    const int2* xp = reinterpret_cast<const int2*>(xyz);

    // prefetch task 0 (rows r0, r0+1); lane l covers j = 2l, 2l+1 (3 int2 per row)
    int2 p0, p1, p2, p3, p4, p5;
    {
        size_t ba = (size_t)192 * r0 + 3 * l;
        size_t bb = (size_t)192 * (r0 + 1) + 3 * l;
        p0 = xp[ba]; p1 = xp[ba + 1]; p2 = xp[ba + 2];
        p3 = xp[bb]; p4 = xp[bb + 1]; p5 = xp[bb + 2];
    }
    __syncthreads();   // the ONLY barrier (table visibility)

    #pragma unroll
    for (int k = 0; k < 2; ++k) {            // 2 tasks x 2 rows = 4 rows per wave
        const int ra = r0 + 2 * k;           // even -> rows (i, i+1) same b-plane
        const int b  = ra >> 7;
        const int i  = ra & 127;

        int2 c0 = p0, c1 = p1, c2 = p2, c3 = p3, c4 = p4, c5 = p5;
        if (k == 0) {                        // prefetch next task's xyz
            size_t ba = (size_t)192 * (ra + 2) + 3 * l;
            size_t bb = (size_t)192 * (ra + 3) + 3 * l;
            p0 = xp[ba]; p1 = xp[ba + 1]; p2 = xp[ba + 2];
            p3 = xp[bb]; p4 = xp[bb + 1]; p5 = xp[bb + 2];
        }

        // ---- compute: 2 row-jobs; lane handles (j0=2l, j1=2l+1) of one row ----
        #pragma unroll
        for (int s = 0; s < 2; ++s) {
            int x0, y0, z0, x1, y1, z1;
            if (s == 0) { x0 = c0.x; y0 = c0.y; z0 = c1.x; x1 = c1.y; y1 = c2.x; z1 = c2.y; }
            else        { x0 = c3.x; y0 = c3.y; z0 = c4.x; x1 = c4.y; y1 = c5.x; z1 = c5.y; }

            int t00 = min(max(x0, -POS_BND), POS_BND) + POS_BND;
            int t01 = min(max(y0, -POS_BND), POS_BND) + POS_BND + RPE_NUM;
            int t02 = min(max(z0, -POS_BND), POS_BND) + POS_BND + 2 * RPE_NUM;
            int t10 = min(max(x1, -POS_BND), POS_BND) + POS_BND;
            int t11 = min(max(y1, -POS_BND), POS_BND) + POS_BND + RPE_NUM;
            int t12 = min(max(z1, -POS_BND), POS_BND) + POS_BND + 2 * RPE_NUM;

            // gathers: j0 half A/B, j1 half A/B  (12 x ds_read_b128)
            uint4 ga0 = *reinterpret_cast<const uint4*>(&lt[t00 * 4]);
            uint4 ga1 = *reinterpret_cast<const uint4*>(&lt[t01 * 4]);
            uint4 ga2 = *reinterpret_cast<const uint4*>(&lt[t02 * 4]);
            uint4 gb0 = *reinterpret_cast<const uint4*>(&lt[HALF_OFF + t00 * 4]);
            uint4 gb1 = *reinterpret_cast<const uint4*>(&lt[HALF_OFF + t01 * 4]);
            uint4 gb2 = *reinterpret_cast<const uint4*>(&lt[HALF_OFF + t02 * 4]);
            uint4 gc0 = *reinterpret_cast<const uint4*>(&lt[t10 * 4]);
            uint4 gc1 = *reinterpret_cast<const uint4*>(&lt[t11 * 4]);
            uint4 gc2 = *reinterpret_cast<const uint4*>(&lt[t12 * 4]);
            uint4 gd0 = *reinterpret_cast<const uint4*>(&lt[HALF_OFF + t10 * 4]);
            uint4 gd1 = *reinterpret_cast<const uint4*>(&lt[HALF_OFF + t11 * 4]);
            uint4 gd2 = *reinterpret_cast<const uint4*>(&lt[HALF_OFF + t12 * 4]);

            // sum 3 axes per head, pack (j0,j1) -> bf16 pair, write su
            // write bank = (s*64+l)%32 -> 2-way (free)
            unsigned* srow = &su[w][0][s * 64 + l];
            srow[ 0*128] = pkbf(blo(ga0.x)+blo(ga1.x)+blo(ga2.x), blo(gc0.x)+blo(gc1.x)+blo(gc2.x));
            srow[ 1*128] = pkbf(bhi(ga0.x)+bhi(ga1.x)+bhi(ga2.x), bhi(gc0.x)+bhi(gc1.x)+bhi(gc2.x));
            srow[ 2*128] = pkbf(blo(ga0.y)+blo(ga1.y)+blo(ga2.y), blo(gc0.y)+blo(gc1.y)+blo(gc2.y));
            srow[ 3*128] = pkbf(bhi(ga0.y)+bhi(ga1.y)+bhi(ga2.y), bhi(gc0.y)+bhi(gc1.y)+bhi(gc2.y));
            srow[ 4*128] = pkbf(blo(ga0.z)+blo(ga1.z)+blo(ga2.z), blo(gc0.z)+blo(gc1.z)+blo(gc2.z));
            srow[ 5*128] = pkbf(bhi(ga0.z)+bhi(ga1.z)+bhi(ga2.z), bhi(gc0.z)+bhi(gc1.z)+bhi(gc2.z));
            srow[ 6*128] = pkbf(blo(ga0.w)+blo(ga1.w)+blo(ga2.w), blo(gc0.w)+blo(gc1.w)+blo(gc2.w));
            srow[ 7*128] = pkbf(bhi(ga0.w)+bhi(ga1.w)+bhi(ga2.w), bhi(gc0.w)+bhi(gc1.w)+bhi(gc2.w));
            srow[ 8*128] = pkbf(blo(gb0.x)+blo(gb1.x)+blo(gb2.x), blo(gd0.x)+blo(gd1.x)+blo(gd2.x));
            srow[ 9*128] = pkbf(bhi(gb0.x)+bhi(gb1.x)+bhi(gb2.x), bhi(gd0.x)+bhi(gd1.x)+bhi(gd2.x));
            srow[10*128] = pkbf(blo(gb0.y)+blo(gb1.y)+blo(gb2.y), blo(gd0.y)+blo(gd1.y)+blo(gd2.y));
            srow[11*128] = pkbf(bhi(gb0.y)+bhi(gb1.y)+bhi(gb2.y), bhi(gd0.y)+bhi(gd1.y)+bhi(gd2.y));
            srow[12*128] = pkbf(blo(gb0.z)+blo(gb1.z)+blo(gb2.z), blo(gd0.z)+blo(gd1.z)+blo(gd2.z));
            srow[13*128] = pkbf(bhi(gb0.z)+bhi(gb1.z)+bhi(gb2.z), bhi(gd0.z)+bhi(gd1.z)+bhi(gd2.z));
            srow[14*128] = pkbf(blo(gb0.w)+blo(gb1.w)+blo(gb2.w), blo(gd0.w)+blo(gd1.w)+blo(gd2.w));
            srow[15*128] = pkbf(bhi(gb0.w)+bhi(gb1.w)+bhi(gb2.w), bhi(gd0.w)+bhi(gd1.w)+bhi(gd2.w));
        }

        // ---- store: per head one fully-contiguous 1KB NT run (rows i, i+1) ----
        // ds_read_b64 at 2l: banks uniformly tiled, conflict-free
        const size_t pbase = ((size_t)b * NH) * (P * P) + (size_t)i * P + 4 * l;
        #pragma unroll
        for (int h = 0; h < NH; ++h) {
            uint2 v = *reinterpret_cast<const uint2*>(&su[w][h][2 * l]);
            floatx4 f = { blo(v.x), bhi(v.x), blo(v.y), bhi(v.y) };
            __builtin_nontemporal_store(f,
                reinterpret_cast<floatx4*>(out + pbase + (size_t)h * (P * P)));
        }
    }
}

extern "C" void kernel_launch(void* const* d_in, const int* in_sizes, int n_in,
                              void* d_out, int out_size, void* d_ws, size_t ws_size,
                              hipStream_t stream) {
    const int*   xyz   = (const int*)d_in[0];
    const float* table = (const float*)d_in[1];
    float*       out   = (float*)d_out;

    const int total_rows = 256 * P;                   // 32768
    const int grid = total_rows / ROWS_PER_BLOCK;     // 2048
    rpe_kernel<<<grid, 256, 0, stream>>>(xyz, table, out);
}